// Round 1
// baseline (279.931 us; speedup 1.0000x reference)
//
#include <hip/hip_runtime.h>
#include <stdint.h>

typedef __attribute__((ext_vector_type(8))) short short8;
typedef __attribute__((ext_vector_type(4))) float f32x4;
typedef unsigned int u32;
typedef unsigned short u16;

static constexpr int N_TOK = 1024;
static constexpr int DDIM = 2048;
static constexpr int FDIM = 1408;
static constexpr int NEXP = 8;
static constexpr int MAXROWS = 3072;   // 2048 real rows + up to 8*127 pad < 3072
static constexpr int MAXTILES = 24;

// ---- workspace byte offsets ----
static constexpr size_t O_META    = 0;                                   // 64 ints
static constexpr size_t O_TEXP    = 256;                                 // MAXTILES ints
static constexpr size_t O_TROW    = 512;                                 // MAXTILES ints
static constexpr size_t O_ROWTOK  = 768;                                 // MAXROWS ints
static constexpr size_t O_TOKROWS = O_ROWTOK + (size_t)MAXROWS * 4;      // 2048 ints
static constexpr size_t O_SEL     = O_TOKROWS + 2048 * 4;                // 2048 ints
static constexpr size_t O_W       = O_SEL + 2048 * 4;                    // 2048 floats
static constexpr size_t O_G       = (O_W + 2048 * 4 + 255) & ~(size_t)255; // MAXROWS*FDIM bf16
static constexpr size_t O_U       = O_G + (size_t)MAXROWS * FDIM * 2;
static constexpr size_t O_EO      = O_U + (size_t)MAXROWS * FDIM * 2;    // MAXROWS*DDIM fp32

static __device__ __forceinline__ u16 f2bf(float f) {
    u32 u = __builtin_bit_cast(u32, f);
    u += 0x7fffu + ((u >> 16) & 1u);          // RNE
    return (u16)(u >> 16);
}
static __device__ __forceinline__ float bf2f(u16 s) {
    u32 u = ((u32)s) << 16;
    return __builtin_bit_cast(float, u);
}
static __device__ __forceinline__ u32 pack2(float a, float b) {
    return (u32)f2bf(a) | ((u32)f2bf(b) << 16);
}

// ---------------- router: logits, top-2, softmax ----------------
__global__ __launch_bounds__(256) void router_kernel(
    const float* __restrict__ x, const float* __restrict__ gw,
    int* __restrict__ sel, float* __restrict__ wout)
{
    __shared__ float xs[DDIM];
    __shared__ float lg[NEXP];
    const int tok = blockIdx.x;
    const float* xr = x + (size_t)tok * DDIM;
    for (int i = threadIdx.x; i < DDIM / 4; i += 256)
        ((float4*)xs)[i] = ((const float4*)xr)[i];
    __syncthreads();
    const int wid = threadIdx.x >> 6, lane = threadIdx.x & 63;
    for (int i = 0; i < 2; i++) {
        const int e = wid * 2 + i;
        const float* g = gw + (size_t)e * DDIM;
        float s = 0.f;
        for (int k = lane; k < DDIM; k += 64) s += xs[k] * g[k];
        for (int off = 32; off > 0; off >>= 1) s += __shfl_down(s, off);
        if (lane == 0) lg[e] = s;
    }
    __syncthreads();
    if (threadIdx.x == 0) {
        int i1 = 0;
        for (int e = 1; e < NEXP; e++) if (lg[e] > lg[i1]) i1 = e;
        int i2 = -1;
        for (int e = 0; e < NEXP; e++) {
            if (e == i1) continue;
            if (i2 < 0 || lg[e] > lg[i2]) i2 = e;
        }
        const float e2 = __expf(lg[i2] - lg[i1]);
        const float w1 = 1.f / (1.f + e2);
        sel[tok * 2] = i1; sel[tok * 2 + 1] = i2;
        wout[tok * 2] = w1; wout[tok * 2 + 1] = e2 * w1;
    }
}

// ---------------- deterministic routing build (1 block, 8 waves) ----------------
__global__ __launch_bounds__(512) void build_kernel(
    const int* __restrict__ sel, const float* __restrict__ w,
    int* __restrict__ meta, int* __restrict__ tile_e, int* __restrict__ tile_r0,
    int* __restrict__ row_tok, int* __restrict__ tok_rows)
{
    __shared__ int s0[N_TOK], s1[N_TOK];
    __shared__ u16 p0[N_TOK], p1[N_TOK];
    __shared__ int counts[NEXP], offs[NEXP];
    for (int i = threadIdx.x; i < N_TOK; i += 512) {
        s0[i] = sel[i * 2]; s1[i] = sel[i * 2 + 1];
    }
    __syncthreads();
    const int e = threadIdx.x >> 6, lane = threadIdx.x & 63;
    int base = 0;
    for (int c = 0; c < N_TOK / 64; c++) {
        const int tk = c * 64 + lane;
        const int slot = (s0[tk] == e) ? 0 : ((s1[tk] == e) ? 1 : -1);
        const unsigned long long m = __ballot(slot >= 0);
        const int pre = __popcll(m & ((1ull << lane) - 1ull));
        if (slot == 0) p0[tk] = (u16)(base + pre);
        else if (slot == 1) p1[tk] = (u16)(base + pre);
        base += __popcll(m);
    }
    if (lane == 0) counts[e] = base;
    __syncthreads();
    if (threadIdx.x == 0) {
        int off = 0, nt = 0;
        for (int q = 0; q < NEXP; q++) {
            offs[q] = off;
            const int pc = (counts[q] + 127) & ~127;
            for (int i = 0; i < pc / 128; i++) { tile_e[nt] = q; tile_r0[nt] = off + i * 128; nt++; }
            off += pc;
        }
        meta[0] = nt; meta[1] = off;
    }
    __syncthreads();
    const int off = offs[e];
    for (int c = 0; c < N_TOK / 64; c++) {
        const int tk = c * 64 + lane;
        const int slot = (s0[tk] == e) ? 0 : ((s1[tk] == e) ? 1 : -1);
        if (slot >= 0) {
            const int row = off + (slot ? p1[tk] : p0[tk]);
            row_tok[row] = tk;
            tok_rows[tk * 2 + slot] = row;
        }
    }
    const int cnt = counts[e];
    const int pc = (cnt + 127) & ~127;
    for (int p = cnt + lane; p < pc; p += 64) row_tok[off + p] = -1;
}

// ---------------- grouped GEMM: C[tile rows][NDIM] = A * B^T ----------------
// A: gathered x fp32 (A_BF16=false) or h bf16 rows (A_BF16=true).  B: fp32 [NEXP][NDIM][KDIM].
template<bool A_BF16, int KDIM, int NDIM, bool C_F32>
__global__ __launch_bounds__(256) void gemm_kernel(
    const void* __restrict__ Asrc, const float* __restrict__ Ball, void* __restrict__ Cout,
    const int* __restrict__ meta, const int* __restrict__ tile_e,
    const int* __restrict__ tile_r0, const int* __restrict__ row_tok)
{
    if ((int)blockIdx.y >= meta[0]) return;
    const int n0 = blockIdx.x * 128;
    const int e = tile_e[blockIdx.y];
    const int r0g = tile_r0[blockIdx.y];
    const float* B = Ball + (size_t)e * NDIM * KDIM;

    __shared__ __align__(16) u16 As[128 * 64];
    __shared__ __align__(16) u16 Bs[128 * 64];

    const int t = threadIdx.x;
    const int cg = t & 7;      // 16B granule within a 64-col row
    const int sr = t >> 3;     // staging row 0..31 (4 rows per thread, stride 32)

    const float* arow_f[4];
    const u16* arow_h[4];
    bool avalid[4];
    for (int i = 0; i < 4; i++) {
        const int r = sr + 32 * i;
        if constexpr (A_BF16) {
            arow_h[i] = (const u16*)Asrc + (size_t)(r0g + r) * KDIM;
            avalid[i] = true; arow_f[i] = nullptr;
        } else {
            const int tok = row_tok[r0g + r];
            avalid[i] = (tok >= 0);
            arow_f[i] = (const float*)Asrc + (size_t)(tok < 0 ? 0 : tok) * KDIM;
            arow_h[i] = nullptr;
        }
    }
    const float* brow[4];
    for (int i = 0; i < 4; i++) brow[i] = B + (size_t)(n0 + sr + 32 * i) * KDIM;

    const int wid = t >> 6, lane = t & 63;
    const int wm = (wid >> 1) * 64, wn = (wid & 1) * 64;
    const int lr = lane & 15, lhi = lane >> 4;

    f32x4 acc[4][4];
    for (int m = 0; m < 4; m++)
        for (int n = 0; n < 4; n++)
            acc[m][n] = f32x4{0.f, 0.f, 0.f, 0.f};

    for (int k0 = 0; k0 < KDIM; k0 += 64) {
        __syncthreads();
        // ---- stage A tile (convert fp32->bf16 on the fly when needed) ----
        for (int i = 0; i < 4; i++) {
            const int r = sr + 32 * i;
            uint4 packed;
            if constexpr (A_BF16) {
                packed = *(const uint4*)(arow_h[i] + k0 + cg * 8);
            } else {
                float4 f0 = make_float4(0.f, 0.f, 0.f, 0.f), f1 = f0;
                if (avalid[i]) {
                    f0 = *(const float4*)(arow_f[i] + k0 + cg * 8);
                    f1 = *(const float4*)(arow_f[i] + k0 + cg * 8 + 4);
                }
                packed.x = pack2(f0.x, f0.y); packed.y = pack2(f0.z, f0.w);
                packed.z = pack2(f1.x, f1.y); packed.w = pack2(f1.z, f1.w);
            }
            *(uint4*)(&As[r * 64 + ((cg ^ (r & 7)) * 8)]) = packed;
        }
        // ---- stage B tile (always fp32 -> bf16) ----
        for (int i = 0; i < 4; i++) {
            const int r = sr + 32 * i;
            const float4 f0 = *(const float4*)(brow[i] + k0 + cg * 8);
            const float4 f1 = *(const float4*)(brow[i] + k0 + cg * 8 + 4);
            uint4 packed;
            packed.x = pack2(f0.x, f0.y); packed.y = pack2(f0.z, f0.w);
            packed.z = pack2(f1.x, f1.y); packed.w = pack2(f1.z, f1.w);
            *(uint4*)(&Bs[r * 64 + ((cg ^ (r & 7)) * 8)]) = packed;
        }
        __syncthreads();
        // ---- MFMA ----
        for (int ks = 0; ks < 2; ks++) {
            short8 a[4], b[4];
            for (int m = 0; m < 4; m++) {
                const int row = wm + m * 16 + lr;
                const int gr = (ks * 4 + lhi) ^ (row & 7);
                a[m] = *(const short8*)(&As[row * 64 + gr * 8]);
            }
            for (int n = 0; n < 4; n++) {
                const int row = wn + n * 16 + lr;
                const int gr = (ks * 4 + lhi) ^ (row & 7);
                b[n] = *(const short8*)(&Bs[row * 64 + gr * 8]);
            }
            for (int m = 0; m < 4; m++)
                for (int n = 0; n < 4; n++)
                    acc[m][n] = __builtin_amdgcn_mfma_f32_16x16x32_bf16(a[m], b[n], acc[m][n], 0, 0, 0);
        }
    }
    // ---- epilogue: C/D layout col=lane&15, row=(lane>>4)*4+reg ----
    for (int m = 0; m < 4; m++) {
        const int rowb = r0g + wm + m * 16 + lhi * 4;
        for (int n = 0; n < 4; n++) {
            const int col = n0 + wn + n * 16 + lr;
            const f32x4 v = acc[m][n];
            if constexpr (C_F32) {
                float* C = (float*)Cout;
                for (int j = 0; j < 4; j++) C[(size_t)(rowb + j) * NDIM + col] = v[j];
            } else {
                u16* C = (u16*)Cout;
                for (int j = 0; j < 4; j++) C[(size_t)(rowb + j) * NDIM + col] = f2bf(v[j]);
            }
        }
    }
}

// ---------------- SwiGLU: h = silu(g) * u, in-place into g ----------------
__global__ __launch_bounds__(256) void swiglu_kernel(
    u16* __restrict__ g, const u16* __restrict__ u, const int* __restrict__ meta)
{
    const long total = (long)meta[0] * 128 * FDIM;
    const long idx = ((long)blockIdx.x * 256 + threadIdx.x) * 8;
    if (idx >= total) return;
    const uint4 gv = *(const uint4*)(g + idx);
    const uint4 uv = *(const uint4*)(u + idx);
    u32 gs[4] = {gv.x, gv.y, gv.z, gv.w};
    u32 us[4] = {uv.x, uv.y, uv.z, uv.w};
    u32 rs[4];
    for (int i = 0; i < 4; i++) {
        const float g0 = bf2f((u16)(gs[i] & 0xffff)), g1 = bf2f((u16)(gs[i] >> 16));
        const float u0 = bf2f((u16)(us[i] & 0xffff)), u1 = bf2f((u16)(us[i] >> 16));
        const float h0 = g0 / (1.f + __expf(-g0)) * u0;
        const float h1 = g1 / (1.f + __expf(-g1)) * u1;
        rs[i] = pack2(h0, h1);
    }
    uint4 r; r.x = rs[0]; r.y = rs[1]; r.z = rs[2]; r.w = rs[3];
    *(uint4*)(g + idx) = r;
}

// ---------------- combine: out[t] = w1*eo[r1] + w2*eo[r2] ----------------
__global__ __launch_bounds__(256) void combine_kernel(
    const float* __restrict__ eo, const int* __restrict__ tok_rows,
    const float* __restrict__ w, float* __restrict__ out)
{
    const int tok = blockIdx.x;
    const int r1 = tok_rows[tok * 2], r2 = tok_rows[tok * 2 + 1];
    const float w1 = w[tok * 2], w2 = w[tok * 2 + 1];
    const int d = threadIdx.x * 8;
    const float4* p1 = (const float4*)(eo + (size_t)r1 * DDIM + d);
    const float4* p2 = (const float4*)(eo + (size_t)r2 * DDIM + d);
    float4* po = (float4*)(out + (size_t)tok * DDIM + d);
    for (int i = 0; i < 2; i++) {
        const float4 a = p1[i], b = p2[i];
        float4 r;
        r.x = w1 * a.x + w2 * b.x; r.y = w1 * a.y + w2 * b.y;
        r.z = w1 * a.z + w2 * b.z; r.w = w1 * a.w + w2 * b.w;
        po[i] = r;
    }
}

extern "C" void kernel_launch(void* const* d_in, const int* in_sizes, int n_in,
                              void* d_out, int out_size, void* d_ws, size_t ws_size,
                              hipStream_t stream) {
    const float* x  = (const float*)d_in[0];
    const float* gw = (const float*)d_in[1];
    const float* gp = (const float*)d_in[2];
    const float* up = (const float*)d_in[3];
    const float* dp = (const float*)d_in[4];
    float* out = (float*)d_out;
    char* ws = (char*)d_ws;

    int*   meta     = (int*)(ws + O_META);
    int*   tile_e   = (int*)(ws + O_TEXP);
    int*   tile_r0  = (int*)(ws + O_TROW);
    int*   row_tok  = (int*)(ws + O_ROWTOK);
    int*   tok_rows = (int*)(ws + O_TOKROWS);
    int*   sel      = (int*)(ws + O_SEL);
    float* w        = (float*)(ws + O_W);
    u16*   g        = (u16*)(ws + O_G);
    u16*   u        = (u16*)(ws + O_U);
    float* eo       = (float*)(ws + O_EO);

    router_kernel<<<N_TOK, 256, 0, stream>>>(x, gw, sel, w);
    build_kernel<<<1, 512, 0, stream>>>(sel, w, meta, tile_e, tile_r0, row_tok, tok_rows);
    gemm_kernel<false, DDIM, FDIM, false>
        <<<dim3(FDIM / 128, MAXTILES), 256, 0, stream>>>(x, gp, g, meta, tile_e, tile_r0, row_tok);
    gemm_kernel<false, DDIM, FDIM, false>
        <<<dim3(FDIM / 128, MAXTILES), 256, 0, stream>>>(x, up, u, meta, tile_e, tile_r0, row_tok);
    swiglu_kernel<<<(MAXROWS * FDIM) / (256 * 8), 256, 0, stream>>>(g, u, meta);
    gemm_kernel<true, FDIM, DDIM, true>
        <<<dim3(DDIM / 128, MAXTILES), 256, 0, stream>>>(g, dp, eo, meta, tile_e, tile_r0, row_tok);
    combine_kernel<<<N_TOK, 256, 0, stream>>>(eo, tok_rows, w, out);
}

// Round 2
// 196.369 us; speedup vs baseline: 1.4255x; 1.4255x over previous
//
#include <hip/hip_runtime.h>
#include <stdint.h>

typedef __attribute__((ext_vector_type(8))) short short8;
typedef __attribute__((ext_vector_type(4))) float f32x4;
typedef unsigned int u32;
typedef unsigned short u16;

static constexpr int N_TOK = 1024;
static constexpr int DDIM = 2048;
static constexpr int FDIM = 1408;
static constexpr int NEXP = 8;
static constexpr int MAXROWS = 3072;   // 2048 real rows + up to 8*127 pad < 3072
static constexpr int MAXTILES = 24;

// ---- workspace byte offsets ----
static constexpr size_t O_META    = 0;                                   // 64 ints
static constexpr size_t O_TEXP    = 256;                                 // MAXTILES ints
static constexpr size_t O_TROW    = 512;                                 // MAXTILES ints
static constexpr size_t O_ROWTOK  = 768;                                 // MAXROWS ints
static constexpr size_t O_TOKROWS = O_ROWTOK + (size_t)MAXROWS * 4;      // 2048 ints
static constexpr size_t O_SEL     = O_TOKROWS + 2048 * 4;                // 2048 ints
static constexpr size_t O_W       = O_SEL + 2048 * 4;                    // 2048 floats
static constexpr size_t O_G       = (O_W + 2048 * 4 + 255) & ~(size_t)255; // MAXROWS*FDIM bf16
static constexpr size_t O_U       = O_G + (size_t)MAXROWS * FDIM * 2;
static constexpr size_t O_EO      = O_U + (size_t)MAXROWS * FDIM * 2;    // MAXROWS*DDIM fp32

static __device__ __forceinline__ u16 f2bf(float f) {
    u32 u = __builtin_bit_cast(u32, f);
    u += 0x7fffu + ((u >> 16) & 1u);          // RNE
    return (u16)(u >> 16);
}
static __device__ __forceinline__ float bf2f(u16 s) {
    u32 u = ((u32)s) << 16;
    return __builtin_bit_cast(float, u);
}
static __device__ __forceinline__ u32 pack2(float a, float b) {
    return (u32)f2bf(a) | ((u32)f2bf(b) << 16);
}

// ---------------- router: logits, top-2, softmax ----------------
__global__ __launch_bounds__(256) void router_kernel(
    const float* __restrict__ x, const float* __restrict__ gw,
    int* __restrict__ sel, float* __restrict__ wout)
{
    __shared__ float xs[DDIM];
    __shared__ float lg[NEXP];
    const int tok = blockIdx.x;
    const float* xr = x + (size_t)tok * DDIM;
    for (int i = threadIdx.x; i < DDIM / 4; i += 256)
        ((float4*)xs)[i] = ((const float4*)xr)[i];
    __syncthreads();
    const int wid = threadIdx.x >> 6, lane = threadIdx.x & 63;
    for (int i = 0; i < 2; i++) {
        const int e = wid * 2 + i;
        const float* g = gw + (size_t)e * DDIM;
        float s = 0.f;
        for (int k = lane; k < DDIM; k += 64) s += xs[k] * g[k];
        for (int off = 32; off > 0; off >>= 1) s += __shfl_down(s, off);
        if (lane == 0) lg[e] = s;
    }
    __syncthreads();
    if (threadIdx.x == 0) {
        int i1 = 0;
        for (int e = 1; e < NEXP; e++) if (lg[e] > lg[i1]) i1 = e;
        int i2 = -1;
        for (int e = 0; e < NEXP; e++) {
            if (e == i1) continue;
            if (i2 < 0 || lg[e] > lg[i2]) i2 = e;
        }
        const float e2 = __expf(lg[i2] - lg[i1]);
        const float w1 = 1.f / (1.f + e2);
        sel[tok * 2] = i1; sel[tok * 2 + 1] = i2;
        wout[tok * 2] = w1; wout[tok * 2 + 1] = e2 * w1;
    }
}

// ---------------- deterministic routing build (1 block, 8 waves) ----------------
__global__ __launch_bounds__(512) void build_kernel(
    const int* __restrict__ sel, const float* __restrict__ w,
    int* __restrict__ meta, int* __restrict__ tile_e, int* __restrict__ tile_r0,
    int* __restrict__ row_tok, int* __restrict__ tok_rows)
{
    __shared__ int s0[N_TOK], s1[N_TOK];
    __shared__ u16 p0[N_TOK], p1[N_TOK];
    __shared__ int counts[NEXP], offs[NEXP];
    for (int i = threadIdx.x; i < N_TOK; i += 512) {
        s0[i] = sel[i * 2]; s1[i] = sel[i * 2 + 1];
    }
    __syncthreads();
    const int e = threadIdx.x >> 6, lane = threadIdx.x & 63;
    int base = 0;
    for (int c = 0; c < N_TOK / 64; c++) {
        const int tk = c * 64 + lane;
        const int slot = (s0[tk] == e) ? 0 : ((s1[tk] == e) ? 1 : -1);
        const unsigned long long m = __ballot(slot >= 0);
        const int pre = __popcll(m & ((1ull << lane) - 1ull));
        if (slot == 0) p0[tk] = (u16)(base + pre);
        else if (slot == 1) p1[tk] = (u16)(base + pre);
        base += __popcll(m);
    }
    if (lane == 0) counts[e] = base;
    __syncthreads();
    if (threadIdx.x == 0) {
        int off = 0, nt = 0;
        for (int q = 0; q < NEXP; q++) {
            offs[q] = off;
            const int pc = (counts[q] + 127) & ~127;
            for (int i = 0; i < pc / 128; i++) { tile_e[nt] = q; tile_r0[nt] = off + i * 128; nt++; }
            off += pc;
        }
        meta[0] = nt; meta[1] = off;
    }
    __syncthreads();
    const int off = offs[e];
    for (int c = 0; c < N_TOK / 64; c++) {
        const int tk = c * 64 + lane;
        const int slot = (s0[tk] == e) ? 0 : ((s1[tk] == e) ? 1 : -1);
        if (slot >= 0) {
            const int row = off + (slot ? p1[tk] : p0[tk]);
            row_tok[row] = tk;
            tok_rows[tk * 2 + slot] = row;
        }
    }
    const int cnt = counts[e];
    const int pc = (cnt + 127) & ~127;
    for (int p = cnt + lane; p < pc; p += 64) row_tok[off + p] = -1;
}

// ---------------- grouped GEMM, 512 threads, 2-deep pipelined ----------------
// C[tile rows][NDIM] = A * B^T.  A: gathered x fp32 (A_BF16=false) or h bf16
// rows (A_BF16=true).  B: fp32 [NEXP][NDIM][KDIM].  DUAL: blockIdx.x selects
// (B0,C0)=gate vs (B1,C1)=up so both GEMMs share one larger grid.
template<bool A_BF16, int KDIM, int NDIM, bool C_F32, bool DUAL>
__global__ __launch_bounds__(512) void gemm_kernel(
    const void* __restrict__ Asrc,
    const float* __restrict__ B0all, const float* __restrict__ B1all,
    void* __restrict__ C0, void* __restrict__ C1,
    const int* __restrict__ meta, const int* __restrict__ tile_e,
    const int* __restrict__ tile_r0, const int* __restrict__ row_tok)
{
    if ((int)blockIdx.y >= meta[0]) return;
    int nb = blockIdx.x;
    const float* Ball = B0all;
    void* Cout = C0;
    if (DUAL && nb >= NDIM / 128) { nb -= NDIM / 128; Ball = B1all; Cout = C1; }
    const int n0 = nb * 128;
    const int e = tile_e[blockIdx.y];
    const int r0g = tile_r0[blockIdx.y];
    const float* B = Ball + (size_t)e * NDIM * KDIM;

    __shared__ __align__(16) u16 As[2][128 * 64];
    __shared__ __align__(16) u16 Bs[2][128 * 64];

    const int t = threadIdx.x;
    // fp32 staging map: thread -> (rows r16+32i, float4-col c4 of 16)
    const int r16 = t >> 4, c4 = t & 15;
    // bf16 staging map: thread -> (rows r8+64i, 16B-granule g8 of 8)
    const int r8 = t >> 3, g8 = t & 7;

    // --- source pointers (include the per-thread column offset) ---
    const float* arow_f[4]; bool avalid[4]; const u16* arow_h[2];
    if constexpr (A_BF16) {
        for (int i = 0; i < 2; i++)
            arow_h[i] = (const u16*)Asrc + (size_t)(r0g + r8 + 64 * i) * KDIM + g8 * 8;
        for (int i = 0; i < 4; i++) { arow_f[i] = nullptr; avalid[i] = true; }
    } else {
        for (int i = 0; i < 4; i++) {
            const int tok = row_tok[r0g + r16 + 32 * i];
            avalid[i] = (tok >= 0);
            arow_f[i] = (const float*)Asrc + (size_t)(tok < 0 ? 0 : tok) * KDIM + c4 * 4;
        }
        for (int i = 0; i < 2; i++) arow_h[i] = nullptr;
    }
    const float* brow[4];
    for (int i = 0; i < 4; i++)
        brow[i] = B + (size_t)(n0 + r16 + 32 * i) * KDIM + c4 * 4;

    // --- swizzled LDS store offsets (u16 units) ---
    int sOff_f[4], sOffA_h[2];
    for (int i = 0; i < 4; i++) {
        const int row = r16 + 32 * i;
        sOff_f[i] = row * 64 + (((c4 >> 1) ^ (row & 7)) * 8) + (c4 & 1) * 4;
    }
    if constexpr (A_BF16) {
        for (int i = 0; i < 2; i++) {
            const int row = r8 + 64 * i;
            sOffA_h[i] = row * 64 + ((g8 ^ (row & 7)) * 8);
        }
    }

    const int wid = t >> 6, lane = t & 63;
    const int wm = (wid >> 2) * 64, wn = (wid & 3) * 32;
    const int lr = lane & 15, lhi = lane >> 4;

    f32x4 acc[4][2];
    for (int m = 0; m < 4; m++)
        for (int n = 0; n < 2; n++)
            acc[m][n] = f32x4{0.f, 0.f, 0.f, 0.f};

    float4 pa[4], pb[4]; uint4 pah[2];

    auto LOAD = [&](int k0) {
        if constexpr (A_BF16) {
            #pragma unroll
            for (int i = 0; i < 2; i++) pah[i] = *(const uint4*)(arow_h[i] + k0);
        } else {
            #pragma unroll
            for (int i = 0; i < 4; i++)
                pa[i] = avalid[i] ? *(const float4*)(arow_f[i] + k0)
                                  : make_float4(0.f, 0.f, 0.f, 0.f);
        }
        #pragma unroll
        for (int i = 0; i < 4; i++) pb[i] = *(const float4*)(brow[i] + k0);
    };
    auto STORE = [&](int bsel) {
        if constexpr (A_BF16) {
            #pragma unroll
            for (int i = 0; i < 2; i++) *(uint4*)(&As[bsel][sOffA_h[i]]) = pah[i];
        } else {
            #pragma unroll
            for (int i = 0; i < 4; i++) {
                uint2 v; v.x = pack2(pa[i].x, pa[i].y); v.y = pack2(pa[i].z, pa[i].w);
                *(uint2*)(&As[bsel][sOff_f[i]]) = v;
            }
        }
        #pragma unroll
        for (int i = 0; i < 4; i++) {
            uint2 v; v.x = pack2(pb[i].x, pb[i].y); v.y = pack2(pb[i].z, pb[i].w);
            *(uint2*)(&Bs[bsel][sOff_f[i]]) = v;
        }
    };
    auto COMPUTE = [&](int bsel) {
        #pragma unroll
        for (int ks = 0; ks < 2; ks++) {
            short8 a[4], b[2];
            #pragma unroll
            for (int m = 0; m < 4; m++) {
                const int row = wm + m * 16 + lr;
                const int gr = (ks * 4 + lhi) ^ (row & 7);
                a[m] = *(const short8*)(&As[bsel][row * 64 + gr * 8]);
            }
            #pragma unroll
            for (int n = 0; n < 2; n++) {
                const int row = wn + n * 16 + lr;
                const int gr = (ks * 4 + lhi) ^ (row & 7);
                b[n] = *(const short8*)(&Bs[bsel][row * 64 + gr * 8]);
            }
            #pragma unroll
            for (int m = 0; m < 4; m++)
                #pragma unroll
                for (int n = 0; n < 2; n++)
                    acc[m][n] = __builtin_amdgcn_mfma_f32_16x16x32_bf16(a[m], b[n], acc[m][n], 0, 0, 0);
        }
    };

    constexpr int NT = KDIM / 64;
    // prologue
    LOAD(0); STORE(0);
    __syncthreads();
    // 2-deep pipeline: issue tile t+1 loads BEFORE computing tile t (T14 split);
    // convert+ds_write land after the MFMA phase; one barrier per K-step.
    for (int kt = 0; kt < NT; kt++) {
        const int cur = kt & 1;
        if (kt + 1 < NT) LOAD((kt + 1) * 64);
        COMPUTE(cur);
        if (kt + 1 < NT) {
            STORE(cur ^ 1);
            __syncthreads();
        }
    }

    // ---- epilogue: C/D layout col=lane&15, row=(lane>>4)*4+reg ----
    for (int m = 0; m < 4; m++) {
        const int rowb = r0g + wm + m * 16 + lhi * 4;
        for (int n = 0; n < 2; n++) {
            const int col = n0 + wn + n * 16 + lr;
            const f32x4 v = acc[m][n];
            if constexpr (C_F32) {
                float* C = (float*)Cout;
                for (int j = 0; j < 4; j++) C[(size_t)(rowb + j) * NDIM + col] = v[j];
            } else {
                u16* C = (u16*)Cout;
                for (int j = 0; j < 4; j++) C[(size_t)(rowb + j) * NDIM + col] = f2bf(v[j]);
            }
        }
    }
}

// ---------------- SwiGLU: h = silu(g) * u, in-place into g ----------------
__global__ __launch_bounds__(256) void swiglu_kernel(
    u16* __restrict__ g, const u16* __restrict__ u, const int* __restrict__ meta)
{
    const long total = (long)meta[0] * 128 * FDIM;
    const long idx = ((long)blockIdx.x * 256 + threadIdx.x) * 8;
    if (idx >= total) return;
    const uint4 gv = *(const uint4*)(g + idx);
    const uint4 uv = *(const uint4*)(u + idx);
    u32 gs[4] = {gv.x, gv.y, gv.z, gv.w};
    u32 us[4] = {uv.x, uv.y, uv.z, uv.w};
    u32 rs[4];
    for (int i = 0; i < 4; i++) {
        const float g0 = bf2f((u16)(gs[i] & 0xffff)), g1 = bf2f((u16)(gs[i] >> 16));
        const float u0 = bf2f((u16)(us[i] & 0xffff)), u1 = bf2f((u16)(us[i] >> 16));
        const float h0 = g0 / (1.f + __expf(-g0)) * u0;
        const float h1 = g1 / (1.f + __expf(-g1)) * u1;
        rs[i] = pack2(h0, h1);
    }
    uint4 r; r.x = rs[0]; r.y = rs[1]; r.z = rs[2]; r.w = rs[3];
    *(uint4*)(g + idx) = r;
}

// ---------------- combine: out[t] = w1*eo[r1] + w2*eo[r2] ----------------
__global__ __launch_bounds__(256) void combine_kernel(
    const float* __restrict__ eo, const int* __restrict__ tok_rows,
    const float* __restrict__ w, float* __restrict__ out)
{
    const int tok = blockIdx.x;
    const int r1 = tok_rows[tok * 2], r2 = tok_rows[tok * 2 + 1];
    const float w1 = w[tok * 2], w2 = w[tok * 2 + 1];
    const int d = threadIdx.x * 8;
    const float4* p1 = (const float4*)(eo + (size_t)r1 * DDIM + d);
    const float4* p2 = (const float4*)(eo + (size_t)r2 * DDIM + d);
    float4* po = (float4*)(out + (size_t)tok * DDIM + d);
    for (int i = 0; i < 2; i++) {
        const float4 a = p1[i], b = p2[i];
        float4 r;
        r.x = w1 * a.x + w2 * b.x; r.y = w1 * a.y + w2 * b.y;
        r.z = w1 * a.z + w2 * b.z; r.w = w1 * a.w + w2 * b.w;
        po[i] = r;
    }
}

extern "C" void kernel_launch(void* const* d_in, const int* in_sizes, int n_in,
                              void* d_out, int out_size, void* d_ws, size_t ws_size,
                              hipStream_t stream) {
    const float* x  = (const float*)d_in[0];
    const float* gw = (const float*)d_in[1];
    const float* gp = (const float*)d_in[2];
    const float* up = (const float*)d_in[3];
    const float* dp = (const float*)d_in[4];
    float* out = (float*)d_out;
    char* ws = (char*)d_ws;

    int*   meta     = (int*)(ws + O_META);
    int*   tile_e   = (int*)(ws + O_TEXP);
    int*   tile_r0  = (int*)(ws + O_TROW);
    int*   row_tok  = (int*)(ws + O_ROWTOK);
    int*   tok_rows = (int*)(ws + O_TOKROWS);
    int*   sel      = (int*)(ws + O_SEL);
    float* w        = (float*)(ws + O_W);
    u16*   g        = (u16*)(ws + O_G);
    u16*   u        = (u16*)(ws + O_U);
    float* eo       = (float*)(ws + O_EO);

    router_kernel<<<N_TOK, 256, 0, stream>>>(x, gw, sel, w);
    build_kernel<<<1, 512, 0, stream>>>(sel, w, meta, tile_e, tile_r0, row_tok, tok_rows);
    // fused gate+up grouped GEMM (22 n-tiles: first 11 -> gate, last 11 -> up)
    gemm_kernel<false, DDIM, FDIM, false, true>
        <<<dim3(2 * (FDIM / 128), MAXTILES), 512, 0, stream>>>(
            x, gp, up, g, u, meta, tile_e, tile_r0, row_tok);
    swiglu_kernel<<<(MAXROWS * FDIM) / (256 * 8), 256, 0, stream>>>(g, u, meta);
    gemm_kernel<true, FDIM, DDIM, true, false>
        <<<dim3(DDIM / 128, MAXTILES), 512, 0, stream>>>(
            g, dp, nullptr, eo, nullptr, meta, tile_e, tile_r0, row_tok);
    combine_kernel<<<N_TOK, 256, 0, stream>>>(eo, tok_rows, w, out);
}